// Round 1
// baseline (415.216 us; speedup 1.0000x reference)
//
#include <hip/hip_runtime.h>
#include <math.h>

#define NCLS 15
constexpr int BB = 8;
constexpr int GG = 60;
constexpr int AA = 21504;   // 128*128 + 64*64 + 32*32
constexpr int REC = 40;     // floats per anchor record
constexpr int GREC = 12;    // floats per gt record
constexpr int TK = 10;

// ---------- helpers ----------

__device__ __forceinline__ float in_val(const float* o8, const float* o16, const float* o32,
                                        int b, int c, int a) {
  if (a < 16384)       return o8 [(size_t)(b*21 + c)*16384 + a];
  else if (a < 20480)  return o16[(size_t)(b*21 + c)*4096  + (a - 16384)];
  else                 return o32[(size_t)(b*21 + c)*1024  + (a - 20480)];
}

__device__ __forceinline__ void ageom(int a, float& xc, float& yc, float& rad) {
  if (a < 16384) {
    int i = a >> 7, j = a & 127;
    xc = (j + 0.5f) * 8.0f;  yc = (i + 0.5f) * 8.0f;  rad = 20.0f;
  } else if (a < 20480) {
    int l = a - 16384; int i = l >> 6, j = l & 63;
    xc = (j + 0.5f) * 16.0f; yc = (i + 0.5f) * 16.0f; rad = 40.0f;
  } else {
    int l = a - 20480; int i = l >> 5, j = l & 31;
    xc = (j + 0.5f) * 32.0f; yc = (i + 0.5f) * 32.0f; rad = 80.0f;
  }
}

// prob_iou with precomputed covariances; b1 = gt, b2 = pred (symmetric in f32)
__device__ __forceinline__ float prob_iou_f(float x1,float y1,float a1,float b1,float c1,float d1,
                                            float x2,float y2,float a2,float b2,float c2,float d2) {
  float dx = x1 - x2, dy = y1 - y2;
  float Av = a1 + a2, Bv = b1 + b2, Cv = c1 + c2;
  float den = Av*Bv - Cv*Cv + 1e-8f;
  float t1 = 0.25f * (Av*dy*dy + Bv*dx*dx) / den;
  float t2 = 0.5f  * (Cv * (-dx) * dy) / den;
  float t3 = 0.5f  * logf(den / (4.0f * sqrtf(d1*d2) + 1e-8f));
  float bd = t1 + t2 + t3;
  bd = fminf(fmaxf(bd, 1e-8f), 100.0f);
  float e = 1.0f - expf(-bd);
  e = fminf(fmaxf(e, 0.0f), 1.0f);
  return 1.0f - sqrtf(e);
}

// cost of pair (gt gr, anchor record r); also outputs valid-masked iou
__device__ __forceinline__ float pair_cost(const float* r, const float* gr, int cd,
                                           float xc, float yc, float rad, float& iou_out) {
  float valid = gr[9];
  float iou = prob_iou_f(gr[0],gr[1],gr[2],gr[3],gr[4],gr[5],
                         r[0], r[1], r[2], r[3], r[4], r[5]);
  if (valid == 0.0f) iou = 0.0f;
  iou_out = iou;
  int gcls = __float_as_int(gr[8]);
  float cc = r[6] + r[8 + gcls];     // S + log1p(-pg)
  cc = cc - r[23 + gcls];            // - log(pg)
  float cost = cc + 3.0f * (-logf(iou + 1e-8f));
  float dx = fabsf(xc - gr[0]), dy = fabsf(yc - gr[1]);
  bool vb = (valid != 0.0f);
  bool ib = (dx < 0.5f*gr[6]) && (dy < 0.5f*gr[7]) && vb;
  bool ic = (dx < rad) && (dy < rad) && vb;
  if (!(ib && ic)) cost += 1e5f;
  if (!cd)         cost += 1e6f;
  if (!vb)         cost += 1e9f;
  return cost;
}

__device__ __forceinline__ float blk_sum(float v, float* sw) {
  for (int o = 32; o > 0; o >>= 1) v += __shfl_down(v, o);
  int wid = threadIdx.x >> 6, lane = threadIdx.x & 63;
  __syncthreads();
  if (lane == 0) sw[wid] = v;
  __syncthreads();
  float rr = 0.0f;
  if (threadIdx.x == 0) rr = sw[0] + sw[1] + sw[2] + sw[3];
  return rr;
}

// ---------- kernels ----------

// per-anchor decode: record = [x,y,covA,covB,covC,covD,S,obj, L1[15]=log1p(-p), L2[15]=log(p)]
__global__ __launch_bounds__(256) void k_decode(const float* o8, const float* o16, const float* o32,
                                                float* rec) {
  int t = blockIdx.x * 256 + threadIdx.x;
  if (t >= BB*AA) return;
  int b = t / AA, a = t - b*AA;
  int W, loc; float s;
  if (a < 16384)      { W = 128; s = 8.0f;  loc = a; }
  else if (a < 20480) { W = 64;  s = 16.0f; loc = a - 16384; }
  else                { W = 32;  s = 32.0f; loc = a - 20480; }
  int i = loc / W, j = loc - i*W;

  float tx  = in_val(o8,o16,o32,b,0,a);
  float ty  = in_val(o8,o16,o32,b,1,a);
  float tw  = in_val(o8,o16,o32,b,2,a);
  float th  = in_val(o8,o16,o32,b,3,a);
  float ang = in_val(o8,o16,o32,b,4,a);
  float obj = in_val(o8,o16,o32,b,5,a);

  float x = (tx + (float)j) * s;
  float y = (ty + (float)i) * s;
  float w = expf(tw) * s;
  float h = expf(th) * s;

  float w2 = w*w / 12.0f, h2 = h*h / 12.0f;
  float cc = cosf(ang), sn = sinf(ang);
  float cA = w2*cc*cc + h2*sn*sn;
  float cB = w2*sn*sn + h2*cc*cc;
  float cC = (w2 - h2)*cc*sn;
  float cD = fmaxf(cA*cB - cC*cC, 0.0f);

  float sobj = 1.0f / (1.0f + expf(-obj));
  float* r = rec + (size_t)t * REC;
  float S = 0.0f;
  for (int c = 0; c < NCLS; c++) {
    float xl = in_val(o8,o16,o32,b,6+c,a);
    float sc = 1.0f / (1.0f + expf(-xl));
    float p  = sqrtf(sc * sobj);
    p = fminf(fmaxf(p, 1e-7f), 1.0f - 1e-7f);
    float l1 = log1pf(-p);
    float l2 = logf(p);
    S += -l1;
    r[8 + c]  = l1;
    r[23 + c] = l2;
  }
  r[0]=x; r[1]=y; r[2]=cA; r[3]=cB; r[4]=cC; r[5]=cD; r[6]=S; r[7]=obj;
}

// gt record = [x,y,covA,covB,covC,covD,w,h,cls(int bits),valid,pad,pad]
__global__ void k_gt(const float* labels, float* grec, float* acc) {
  int t = blockIdx.x * 64 + threadIdx.x;
  if (t >= BB*GG) return;
  const float* L = labels + (size_t)t * 6;
  float s = 0.0f;
  for (int k = 0; k < 6; k++) s += L[k];
  float valid = (s > 0.0f) ? 1.0f : 0.0f;
  float x = L[1], y = L[2], w = L[3], h = L[4], ang = L[5];
  float w2 = w*w / 12.0f, h2 = h*h / 12.0f;
  float cc = cosf(ang), sn = sinf(ang);
  float cA = w2*cc*cc + h2*sn*sn;
  float cB = w2*sn*sn + h2*cc*cc;
  float cC = (w2 - h2)*cc*sn;
  float cD = fmaxf(cA*cB - cC*cC, 0.0f);
  float* gr = grec + (size_t)t * GREC;
  gr[0]=x; gr[1]=y; gr[2]=cA; gr[3]=cB; gr[4]=cC; gr[5]=cD;
  gr[6]=w; gr[7]=h; gr[8]=__int_as_float((int)L[0]); gr[9]=valid; gr[10]=0.0f; gr[11]=0.0f;
  if (valid != 0.0f) atomicAdd(&acc[4], 1.0f);
}

// cand[b,a] = OR over g of (in_box | in_ctr)
__global__ __launch_bounds__(256) void k_cand(const float* grec, int* cand) {
  int t = blockIdx.x * 256 + threadIdx.x;
  if (t >= BB*AA) return;
  int b = t / AA, a = t - b*AA;
  float xc, yc, rad; ageom(a, xc, yc, rad);
  const float* gb = grec + (size_t)b * GG * GREC;
  int c = 0;
  for (int g = 0; g < GG; g++) {
    const float* gr = gb + g*GREC;
    if (gr[9] != 0.0f) {
      float dx = fabsf(xc - gr[0]), dy = fabsf(yc - gr[1]);
      bool ib = (dx < 0.5f*gr[6]) && (dy < 0.5f*gr[7]);
      bool ic = (dx < rad) && (dy < rad);
      if (ib || ic) { c = 1; break; }
    }
  }
  cand[t] = c;
}

// one block per (b,g): top-10 min-cost anchors (stable tiebreak) + top-10 iou_c sum -> dyn_k
__global__ __launch_bounds__(256) void k_assign(const float* rec, const float* grec, const int* cand,
                                                int* mcount, int* mgsum) {
  int bg = blockIdx.x;
  int b = bg / GG;
  const float* gr = grec + (size_t)bg * GREC;
  if (gr[9] == 0.0f) return;  // dyn_k = 0
  int g = bg - b*GG;

  float cst[TK]; int cid[TK]; float vio[TK];
  #pragma unroll
  for (int k = 0; k < TK; k++) { cst[k] = 3.4e38f; cid[k] = 0x7fffffff; vio[k] = -1.0f; }

  const float* recb = rec + (size_t)b * AA * REC;
  const int* candb = cand + (size_t)b * AA;

  for (int a = threadIdx.x; a < AA; a += 256) {
    const float* r = recb + (size_t)a * REC;
    float xc, yc, rad; ageom(a, xc, yc, rad);
    float iou;
    int cd = candb[a];
    float cost = pair_cost(r, gr, cd, xc, yc, rad, iou);
    float iou_c = cd ? iou : 0.0f;
    if (iou_c > vio[TK-1]) {
      int k = TK-1;
      while (k > 0 && iou_c > vio[k-1]) { vio[k] = vio[k-1]; k--; }
      vio[k] = iou_c;
    }
    if (cost < cst[TK-1] || (cost == cst[TK-1] && a < cid[TK-1])) {
      int k = TK-1;
      while (k > 0 && (cost < cst[k-1] || (cost == cst[k-1] && a < cid[k-1]))) {
        cst[k] = cst[k-1]; cid[k] = cid[k-1]; k--;
      }
      cst[k] = cost; cid[k] = a;
    }
  }

  __shared__ float sh_c[128*TK];
  __shared__ int   sh_i[128*TK];
  __shared__ float sh_v[128*TK];
  int tid = threadIdx.x;
  for (int step = 128; step > 0; step >>= 1) {
    if (tid >= step && tid < (step << 1)) {
      int base = (tid - step) * TK;
      #pragma unroll
      for (int k = 0; k < TK; k++) { sh_c[base+k]=cst[k]; sh_i[base+k]=cid[k]; sh_v[base+k]=vio[k]; }
    }
    __syncthreads();
    if (tid < step) {
      int base = tid * TK;
      float nc[TK]; int ni[TK];
      int pi = 0, pj = 0;
      #pragma unroll
      for (int k = 0; k < TK; k++) {
        float oc = sh_c[base+pj]; int oi = sh_i[base+pj];
        bool tm = (cst[pi] < oc) || (cst[pi] == oc && cid[pi] < oi);
        if (tm) { nc[k] = cst[pi]; ni[k] = cid[pi]; pi++; }
        else    { nc[k] = oc;      ni[k] = oi;      pj++; }
      }
      #pragma unroll
      for (int k = 0; k < TK; k++) { cst[k] = nc[k]; cid[k] = ni[k]; }
      float nv[TK]; pi = 0; pj = 0;
      #pragma unroll
      for (int k = 0; k < TK; k++) {
        float ov = sh_v[base+pj];
        if (vio[pi] >= ov) { nv[k] = vio[pi]; pi++; } else { nv[k] = ov; pj++; }
      }
      #pragma unroll
      for (int k = 0; k < TK; k++) vio[k] = nv[k];
    }
    __syncthreads();
  }

  if (tid == 0) {
    float ts = 0.0f;
    #pragma unroll
    for (int k = 0; k < TK; k++) ts += vio[k];
    int dynk = (int)ts;
    if (dynk < 1) dynk = 1;
    if (dynk > TK) dynk = TK;
    int* mc = mcount + (size_t)b * AA;
    int* mg = mgsum  + (size_t)b * AA;
    for (int r = 0; r < dynk; r++) {
      int a = cid[r];
      atomicAdd(&mc[a], 1);
      atomicAdd(&mg[a], g);
    }
  }
}

// per-anchor conflict resolution + loss contributions
__global__ __launch_bounds__(256) void k_losses(const float* o8, const float* o16, const float* o32,
                                                const float* rec, const float* grec,
                                                const int* cand, const int* mcount, const int* mgsum,
                                                float* acc) {
  int t = blockIdx.x * 256 + threadIdx.x;
  int b = t / AA, a = t - b*AA;
  const float* r = rec + (size_t)t * REC;
  int cnt = mcount[t];
  float fg = (cnt > 0) ? 1.0f : 0.0f;
  float obj = r[7];
  float lobj = fmaxf(obj, 0.0f) - obj*fg + log1pf(expf(-fabsf(obj)));
  float liou = 0.0f, lcls = 0.0f;

  if (cnt > 0) {
    int gstar;
    if (cnt == 1) {
      gstar = mgsum[t];
    } else {
      float xc, yc, rad; ageom(a, xc, yc, rad);
      int cd = cand[t];
      float best = 3.4e38f; gstar = 0;
      for (int g = 0; g < GG; g++) {
        const float* gr = grec + (size_t)(b*GG + g) * GREC;
        float iou;
        float cost = pair_cost(r, gr, cd, xc, yc, rad, iou);
        if (cost < best) { best = cost; gstar = g; }
      }
    }
    const float* gr = grec + (size_t)(b*GG + gstar) * GREC;
    float I = prob_iou_f(gr[0],gr[1],gr[2],gr[3],gr[4],gr[5],
                         r[0], r[1], r[2], r[3], r[4], r[5]);
    if (gr[9] == 0.0f) I = 0.0f;
    liou = 1.0f - I;
    int gcls = __float_as_int(gr[8]);
    for (int c = 0; c < NCLS; c++) {
      float xl = in_val(o8,o16,o32,b,6+c,a);
      float tgt = (c == gcls) ? I : 0.0f;
      lcls += fmaxf(xl, 0.0f) - xl*tgt + log1pf(expf(-fabsf(xl)));
    }
  }

  __shared__ float sw[4];
  float v;
  v = blk_sum(fg,   sw); if (threadIdx.x == 0) atomicAdd(&acc[0], v);
  v = blk_sum(liou, sw); if (threadIdx.x == 0) atomicAdd(&acc[1], v);
  v = blk_sum(lobj, sw); if (threadIdx.x == 0) atomicAdd(&acc[2], v);
  v = blk_sum(lcls, sw); if (threadIdx.x == 0) atomicAdd(&acc[3], v);
}

__global__ void k_fin(const float* acc, float* out) {
  if (threadIdx.x == 0 && blockIdx.x == 0) {
    float nfg = acc[0];
    float nf  = fmaxf(nfg, 1.0f);
    float li = acc[1] / nf;
    float lo = acc[2] / nf;
    float lc = acc[3] / nf;
    float l5 = 5.0f * li;
    out[0] = l5 + lo + lc;
    out[1] = l5;
    out[2] = lo;
    out[3] = lc;
    out[4] = 0.0f;
    out[5] = nfg / fmaxf(acc[4], 1.0f);
  }
}

// ---------- launch ----------

extern "C" void kernel_launch(void* const* d_in, const int* in_sizes, int n_in,
                              void* d_out, int out_size, void* d_ws, size_t ws_size,
                              hipStream_t stream) {
  const float* o8     = (const float*)d_in[0];
  const float* o16    = (const float*)d_in[1];
  const float* o32    = (const float*)d_in[2];
  const float* labels = (const float*)d_in[3];
  float* out = (float*)d_out;

  char* w = (char*)d_ws;
  float* rec  = (float*)w; w += (size_t)BB*AA*REC*sizeof(float);
  float* grec = (float*)w; w += (size_t)BB*GG*GREC*sizeof(float);
  int* cand   = (int*)w;   w += (size_t)BB*AA*sizeof(int);
  int* mcount = (int*)w;   w += (size_t)BB*AA*sizeof(int);
  int* mgsum  = (int*)w;   w += (size_t)BB*AA*sizeof(int);
  float* acc  = (float*)w; w += 64;

  // zero mcount+mgsum+acc (contiguous)
  hipMemsetAsync(mcount, 0, (size_t)BB*AA*sizeof(int)*2 + 64, stream);

  int nBA = BB*AA;  // 172032 = 672*256
  k_decode<<<nBA/256, 256, 0, stream>>>(o8, o16, o32, rec);
  k_gt<<<(BB*GG + 63)/64, 64, 0, stream>>>(labels, grec, acc);
  k_cand<<<nBA/256, 256, 0, stream>>>(grec, cand);
  k_assign<<<BB*GG, 256, 0, stream>>>(rec, grec, cand, mcount, mgsum);
  k_losses<<<nBA/256, 256, 0, stream>>>(o8, o16, o32, rec, grec, cand, mcount, mgsum, acc);
  k_fin<<<1, 64, 0, stream>>>(acc, out);
}

// Round 2
// 339.306 us; speedup vs baseline: 1.2237x; 1.2237x over previous
//
#include <hip/hip_runtime.h>
#include <math.h>

#define NCLS 15
constexpr int BB = 8;
constexpr int GG = 60;
constexpr int AA = 21504;   // 128*128 + 64*64 + 32*32
constexpr int TK = 10;
constexpr int SPLIT = 4;
constexpr int SUB = AA / SPLIT;  // 5376
constexpr int GREC = 12;

// ---------- helpers ----------

__device__ __forceinline__ float in_val(const float* o8, const float* o16, const float* o32,
                                        int b, int c, int a) {
  if (a < 16384)       return o8 [(size_t)(b*21 + c)*16384 + a];
  else if (a < 20480)  return o16[(size_t)(b*21 + c)*4096  + (a - 16384)];
  else                 return o32[(size_t)(b*21 + c)*1024  + (a - 20480)];
}

__device__ __forceinline__ void ageom(int a, float& xc, float& yc, float& rad) {
  if (a < 16384) {
    int i = a >> 7, j = a & 127;
    xc = (j + 0.5f) * 8.0f;  yc = (i + 0.5f) * 8.0f;  rad = 20.0f;
  } else if (a < 20480) {
    int l = a - 16384; int i = l >> 6, j = l & 63;
    xc = (j + 0.5f) * 16.0f; yc = (i + 0.5f) * 16.0f; rad = 40.0f;
  } else {
    int l = a - 20480; int i = l >> 5, j = l & 31;
    xc = (j + 0.5f) * 32.0f; yc = (i + 0.5f) * 32.0f; rad = 80.0f;
  }
}

__device__ __forceinline__ float prob_iou_f(float x1,float y1,float a1,float b1,float c1,float d1,
                                            float x2,float y2,float a2,float b2,float c2,float d2) {
  float dx = x1 - x2, dy = y1 - y2;
  float Av = a1 + a2, Bv = b1 + b2, Cv = c1 + c2;
  float den = Av*Bv - Cv*Cv + 1e-8f;
  float t1 = 0.25f * (Av*dy*dy + Bv*dx*dx) / den;
  float t2 = 0.5f  * (Cv * (-dx) * dy) / den;
  float t3 = 0.5f  * logf(den / (4.0f * sqrtf(d1*d2) + 1e-8f));
  float bd = t1 + t2 + t3;
  bd = fminf(fmaxf(bd, 1e-8f), 100.0f);
  float e = 1.0f - expf(-bd);
  e = fminf(fmaxf(e, 0.0f), 1.0f);
  return 1.0f - sqrtf(e);
}

// static-index insertion (register-resident; rule #20)
__device__ __forceinline__ void ins_cost(float (&cst)[TK], int (&cid)[TK], float c, int id) {
  bool ins = (c < cst[TK-1]) || (c == cst[TK-1] && id < cid[TK-1]);
  if (ins) {
    cst[TK-1] = c; cid[TK-1] = id;
    #pragma unroll
    for (int k = TK-1; k > 0; k--) {
      float tc = cst[k-1]; int ti = cid[k-1];
      bool sw = (cst[k] < tc) || (cst[k] == tc && cid[k] < ti);
      if (sw) { cst[k-1] = cst[k]; cid[k-1] = cid[k]; cst[k] = tc; cid[k] = ti; }
    }
  }
}

__device__ __forceinline__ void ins_vio(float (&vio)[TK], float v) {
  if (v > vio[TK-1]) {
    vio[TK-1] = v;
    #pragma unroll
    for (int k = TK-1; k > 0; k--) {
      float tv = vio[k-1];
      bool sw = vio[k] > tv;
      if (sw) { vio[k-1] = vio[k]; vio[k] = tv; }
    }
  }
}

__device__ __forceinline__ float blk_sum(float v, float* sw) {
  for (int o = 32; o > 0; o >>= 1) v += __shfl_down(v, o);
  int wid = threadIdx.x >> 6, lane = threadIdx.x & 63;
  __syncthreads();
  if (lane == 0) sw[wid] = v;
  __syncthreads();
  float rr = 0.0f;
  if (threadIdx.x == 0) rr = sw[0] + sw[1] + sw[2] + sw[3];
  return rr;
}

// ---------- kernels ----------

// gt record = [x,y,covA,covB,covC,covD,w,h,cls(int bits),valid,pad,pad]
__global__ void k_gt(const float* labels, float* grec, float* acc) {
  int t = blockIdx.x * 256 + threadIdx.x;
  if (t >= BB*GG) return;
  const float* L = labels + (size_t)t * 6;
  float s = 0.0f;
  for (int k = 0; k < 6; k++) s += L[k];
  float valid = (s > 0.0f) ? 1.0f : 0.0f;
  float x = L[1], y = L[2], w = L[3], h = L[4], ang = L[5];
  float w2 = w*w / 12.0f, h2 = h*h / 12.0f;
  float cc = cosf(ang), sn = sinf(ang);
  float cA = w2*cc*cc + h2*sn*sn;
  float cB = w2*sn*sn + h2*cc*cc;
  float cC = (w2 - h2)*cc*sn;
  float cD = fmaxf(cA*cB - cC*cC, 0.0f);
  float* gr = grec + (size_t)t * GREC;
  gr[0]=x; gr[1]=y; gr[2]=cA; gr[3]=cB; gr[4]=cC; gr[5]=cD;
  gr[6]=w; gr[7]=h; gr[8]=__int_as_float((int)L[0]); gr[9]=valid; gr[10]=0.0f; gr[11]=0.0f;
  if (valid != 0.0f) atomicAdd(&acc[4], 1.0f);
}

// decode + cand. rec8 = [x,y,cA,cB,cC,cD,S,obj]; L1p/L2p = [b][c][a] planes
__global__ __launch_bounds__(256) void k_decode(const float* o8, const float* o16, const float* o32,
                                                const float* grec,
                                                float* rec8, float* L1p, float* L2p, int* cand) {
  int t = blockIdx.x * 256 + threadIdx.x;
  if (t >= BB*AA) return;
  int b = t / AA, a = t - b*AA;
  int W, loc; float s;
  if (a < 16384)      { W = 128; s = 8.0f;  loc = a; }
  else if (a < 20480) { W = 64;  s = 16.0f; loc = a - 16384; }
  else                { W = 32;  s = 32.0f; loc = a - 20480; }
  int i = loc / W, j = loc - i*W;

  float tx  = in_val(o8,o16,o32,b,0,a);
  float ty  = in_val(o8,o16,o32,b,1,a);
  float tw  = in_val(o8,o16,o32,b,2,a);
  float th  = in_val(o8,o16,o32,b,3,a);
  float ang = in_val(o8,o16,o32,b,4,a);
  float obj = in_val(o8,o16,o32,b,5,a);

  float x = (tx + (float)j) * s;
  float y = (ty + (float)i) * s;
  float w = expf(tw) * s;
  float h = expf(th) * s;

  float w2 = w*w / 12.0f, h2 = h*h / 12.0f;
  float cc = cosf(ang), sn = sinf(ang);
  float cA = w2*cc*cc + h2*sn*sn;
  float cB = w2*sn*sn + h2*cc*cc;
  float cC = (w2 - h2)*cc*sn;
  float cD = fmaxf(cA*cB - cC*cC, 0.0f);

  float sobj = 1.0f / (1.0f + expf(-obj));
  float S = 0.0f;
  for (int c = 0; c < NCLS; c++) {
    float xl = in_val(o8,o16,o32,b,6+c,a);
    float sc = 1.0f / (1.0f + expf(-xl));
    float p  = sqrtf(sc * sobj);
    p = fminf(fmaxf(p, 1e-7f), 1.0f - 1e-7f);
    float l1 = log1pf(-p);
    float l2 = logf(p);
    S += -l1;
    L1p[((size_t)b*NCLS + c)*AA + a] = l1;
    L2p[((size_t)b*NCLS + c)*AA + a] = l2;
  }
  float4* r4 = (float4*)(rec8 + (size_t)t * 8);
  r4[0] = make_float4(x, y, cA, cB);
  r4[1] = make_float4(cC, cD, S, obj);

  // cand = OR over g of (in_box | in_ctr)
  float xc, yc, rad; ageom(a, xc, yc, rad);
  const float* gb = grec + (size_t)b * GG * GREC;
  int cf = 0;
  for (int g = 0; g < GG; g++) {
    const float* gr = gb + g*GREC;
    if (gr[9] != 0.0f) {
      float dx = fabsf(xc - gr[0]), dy = fabsf(yc - gr[1]);
      bool ib = (dx < 0.5f*gr[6]) && (dy < 0.5f*gr[7]);
      bool ic = (dx < rad) && (dy < rad);
      if (ib || ic) { cf = 1; break; }
    }
  }
  cand[t] = cf;
}

// one block per (b,g,split): partial top-10 cost list + top-10 iou list
__global__ __launch_bounds__(256) void k_assign_part(const float* rec8, const float* grec, const int* cand,
                                                     const float* L1p, const float* L2p,
                                                     float* part_c, int* part_i, float* part_v) {
  int blk = blockIdx.x;
  int bg = blk / SPLIT, sp = blk - bg*SPLIT;
  int b = bg / GG;
  const float* gr = grec + (size_t)bg * GREC;
  if (gr[9] == 0.0f) return;  // dyn_k = 0, merge skips too

  float gx = gr[0], gy = gr[1], gA = gr[2], gB = gr[3], gC = gr[4], gD = gr[5];
  float gw = gr[6], gh = gr[7];
  int gcls = __float_as_int(gr[8]);

  __shared__ int s_nboth;
  if (threadIdx.x == 0) s_nboth = 0;
  __syncthreads();

  float cst[TK]; int cid[TK]; float vio[TK];
  #pragma unroll
  for (int k = 0; k < TK; k++) { cst[k] = 3.4e38f; cid[k] = 0x7fffffff; vio[k] = -1.0f; }

  const float* recb = rec8 + (size_t)b * AA * 8;
  const int*  candb = cand + (size_t)b * AA;
  const float* l1p  = L1p + ((size_t)b*NCLS + gcls)*AA;
  const float* l2p  = L2p + ((size_t)b*NCLS + gcls)*AA;

  int a0 = sp * SUB;
  for (int a = a0 + (int)threadIdx.x; a < a0 + SUB; a += 256) {
    float xc, yc, rad; ageom(a, xc, yc, rad);
    float dx = fabsf(xc - gx), dy = fabsf(yc - gy);
    bool both = (dx < 0.5f*gw) && (dy < 0.5f*gh) && (dx < rad) && (dy < rad);
    int cd = candb[a];
    int nb = *((volatile int*)&s_nboth);
    if (!both && nb >= TK) {
      // cost ≥ 1e5-1 > any of block's 10 best (all < 425) → cost path provably prunable
      if (cd) {
        const float4* r4 = (const float4*)(recb + (size_t)a * 8);
        float4 v0 = r4[0], v1 = r4[1];
        float iou = prob_iou_f(gx,gy,gA,gB,gC,gD, v0.x,v0.y,v0.z,v0.w,v1.x,v1.y);
        ins_vio(vio, iou);
      } else {
        if (vio[TK-1] < 0.0f) ins_vio(vio, 0.0f);
      }
      continue;
    }
    const float4* r4 = (const float4*)(recb + (size_t)a * 8);
    float4 v0 = r4[0], v1 = r4[1];
    float iou = prob_iou_f(gx,gy,gA,gB,gC,gD, v0.x,v0.y,v0.z,v0.w,v1.x,v1.y);
    float iou_c = cd ? iou : 0.0f;
    if (iou_c > vio[TK-1]) ins_vio(vio, iou_c);
    float l1 = l1p[a], l2 = l2p[a];
    float ccost = (v1.z + l1) - l2;                    // (S + log1p(-pg)) - log(pg)
    float cost = ccost + 3.0f * (-logf(iou + 1e-8f));
    if (!both) cost += 1e5f;
    if (!cd)   cost += 1e6f;
    ins_cost(cst, cid, cost, a);
    if (both) atomicAdd(&s_nboth, 1);
  }

  // block tree-merge: lists go through LDS (runtime idx ok there), outputs static-indexed
  __shared__ float sh_c[256*TK];
  __shared__ int   sh_i[256*TK];
  __shared__ float sh_v[256*TK];
  int tid = threadIdx.x;
  for (int step = 128; step >= 1; step >>= 1) {
    if (tid < (step << 1)) {
      #pragma unroll
      for (int k = 0; k < TK; k++) {
        sh_c[tid*TK+k] = cst[k]; sh_i[tid*TK+k] = cid[k]; sh_v[tid*TK+k] = vio[k];
      }
    }
    __syncthreads();
    if (tid < step) {
      int ba = tid*TK, bb = (tid + step)*TK;
      float nc[TK]; int ni[TK]; float nv[TK];
      int pi = 0, pj = 0;
      #pragma unroll
      for (int k = 0; k < TK; k++) {
        float ca = sh_c[ba+pi]; int ia = sh_i[ba+pi];
        float cb = sh_c[bb+pj]; int ib = sh_i[bb+pj];
        bool ta = (ca < cb) || (ca == cb && ia < ib);
        nc[k] = ta ? ca : cb; ni[k] = ta ? ia : ib;
        pi += ta ? 1 : 0; pj += ta ? 0 : 1;
      }
      int qi = 0, qj = 0;
      #pragma unroll
      for (int k = 0; k < TK; k++) {
        float va = sh_v[ba+qi], vb = sh_v[bb+qj];
        bool ta = va >= vb;
        nv[k] = ta ? va : vb;
        qi += ta ? 1 : 0; qj += ta ? 0 : 1;
      }
      #pragma unroll
      for (int k = 0; k < TK; k++) { cst[k] = nc[k]; cid[k] = ni[k]; vio[k] = nv[k]; }
    }
    __syncthreads();
  }

  if (tid == 0) {
    float* pc = part_c + (size_t)blk * TK;
    int*   pi = part_i + (size_t)blk * TK;
    float* pv = part_v + (size_t)blk * TK;
    #pragma unroll
    for (int k = 0; k < TK; k++) { pc[k] = cst[k]; pi[k] = cid[k]; pv[k] = vio[k]; }
  }
}

// merge SPLIT partial lists per (b,g): dyn_k + match atomics
__global__ void k_merge(const float* grec, const float* part_c, const int* part_i, const float* part_v,
                        int* mcount, int* mgsum) {
  int t = blockIdx.x * 256 + threadIdx.x;
  if (t >= BB*GG) return;
  const float* gr = grec + (size_t)t * GREC;
  if (gr[9] == 0.0f) return;
  int b = t / GG, g = t - b*GG;
  const float* pc = part_c + (size_t)t * SPLIT * TK;
  const int*   pi = part_i + (size_t)t * SPLIT * TK;
  const float* pv = part_v + (size_t)t * SPLIT * TK;

  // top-10 iou sum (descending merge of 4 sorted lists)
  int q0=0,q1=0,q2=0,q3=0;
  float vs = 0.0f;
  for (int k = 0; k < TK; k++) {
    float b0 = pv[0*TK+q0], b1 = pv[1*TK+q1], b2 = pv[2*TK+q2], b3 = pv[3*TK+q3];
    int sel = 0; float bv = b0;
    if (b1 > bv) { bv = b1; sel = 1; }
    if (b2 > bv) { bv = b2; sel = 2; }
    if (b3 > bv) { bv = b3; sel = 3; }
    vs += bv;
    if (sel==0) q0++; else if (sel==1) q1++; else if (sel==2) q2++; else q3++;
  }
  int dynk = (int)vs;
  if (dynk < 1) dynk = 1;
  if (dynk > TK) dynk = TK;

  int* mc = mcount + (size_t)b * AA;
  int* mg = mgsum  + (size_t)b * AA;
  int p0=0,p1=0,p2=0,p3=0;
  for (int k = 0; k < dynk; k++) {
    float c0 = pc[0*TK+p0]; int i0 = pi[0*TK+p0];
    float c1 = pc[1*TK+p1]; int i1 = pi[1*TK+p1];
    float c2 = pc[2*TK+p2]; int i2 = pi[2*TK+p2];
    float c3 = pc[3*TK+p3]; int i3 = pi[3*TK+p3];
    int sel = 0; float bc = c0; int bi = i0;
    if (c1 < bc || (c1 == bc && i1 < bi)) { bc = c1; bi = i1; sel = 1; }
    if (c2 < bc || (c2 == bc && i2 < bi)) { bc = c2; bi = i2; sel = 2; }
    if (c3 < bc || (c3 == bc && i3 < bi)) { bc = c3; bi = i3; sel = 3; }
    if (sel==0) p0++; else if (sel==1) p1++; else if (sel==2) p2++; else p3++;
    atomicAdd(&mc[bi], 1);
    atomicAdd(&mg[bi], g);
  }
}

// per-anchor conflict resolution + loss contributions
__global__ __launch_bounds__(256) void k_losses(const float* o8, const float* o16, const float* o32,
                                                const float* rec8, const float* grec,
                                                const int* cand, const int* mcount, const int* mgsum,
                                                const float* L1p, const float* L2p, float* acc) {
  int t = blockIdx.x * 256 + threadIdx.x;
  int b = t / AA, a = t - b*AA;
  const float4* r4 = (const float4*)(rec8 + (size_t)t * 8);
  float4 v0 = r4[0], v1 = r4[1];
  int cnt = mcount[t];
  float fg = (cnt > 0) ? 1.0f : 0.0f;
  float obj = v1.w;
  float lobj = fmaxf(obj, 0.0f) - obj*fg + log1pf(expf(-fabsf(obj)));
  float liou = 0.0f, lcls = 0.0f;

  if (cnt > 0) {
    int gstar;
    if (cnt == 1) {
      gstar = mgsum[t];
    } else {
      float xc, yc, rad; ageom(a, xc, yc, rad);
      int cd = cand[t];
      float best = 3.4e38f; gstar = 0;
      for (int g = 0; g < GG; g++) {
        const float* gg = grec + (size_t)(b*GG + g) * GREC;
        float valid = gg[9];
        float iou = prob_iou_f(gg[0],gg[1],gg[2],gg[3],gg[4],gg[5],
                               v0.x,v0.y,v0.z,v0.w,v1.x,v1.y);
        if (valid == 0.0f) iou = 0.0f;
        int gcls = __float_as_int(gg[8]);
        float l1 = L1p[((size_t)b*NCLS + gcls)*AA + a];
        float l2 = L2p[((size_t)b*NCLS + gcls)*AA + a];
        float ccost = (v1.z + l1) - l2;
        float cost = ccost + 3.0f * (-logf(iou + 1e-8f));
        float dx = fabsf(xc - gg[0]), dy = fabsf(yc - gg[1]);
        bool vb = (valid != 0.0f);
        bool ib = (dx < 0.5f*gg[6]) && (dy < 0.5f*gg[7]) && vb;
        bool ic = (dx < rad) && (dy < rad) && vb;
        if (!(ib && ic)) cost += 1e5f;
        if (!cd)         cost += 1e6f;
        if (!vb)         cost += 1e9f;
        if (cost < best) { best = cost; gstar = g; }
      }
    }
    const float* gg = grec + (size_t)(b*GG + gstar) * GREC;
    float I = prob_iou_f(gg[0],gg[1],gg[2],gg[3],gg[4],gg[5],
                         v0.x,v0.y,v0.z,v0.w,v1.x,v1.y);
    if (gg[9] == 0.0f) I = 0.0f;
    liou = 1.0f - I;
    int gcls = __float_as_int(gg[8]);
    for (int c = 0; c < NCLS; c++) {
      float xl = in_val(o8,o16,o32,b,6+c,a);
      float tgt = (c == gcls) ? I : 0.0f;
      lcls += fmaxf(xl, 0.0f) - xl*tgt + log1pf(expf(-fabsf(xl)));
    }
  }

  __shared__ float sw[4];
  float v;
  v = blk_sum(fg,   sw); if (threadIdx.x == 0) atomicAdd(&acc[0], v);
  v = blk_sum(liou, sw); if (threadIdx.x == 0) atomicAdd(&acc[1], v);
  v = blk_sum(lobj, sw); if (threadIdx.x == 0) atomicAdd(&acc[2], v);
  v = blk_sum(lcls, sw); if (threadIdx.x == 0) atomicAdd(&acc[3], v);
}

__global__ void k_fin(const float* acc, float* out) {
  if (threadIdx.x == 0 && blockIdx.x == 0) {
    float nfg = acc[0];
    float nf  = fmaxf(nfg, 1.0f);
    float li = acc[1] / nf;
    float lo = acc[2] / nf;
    float lc = acc[3] / nf;
    float l5 = 5.0f * li;
    out[0] = l5 + lo + lc;
    out[1] = l5;
    out[2] = lo;
    out[3] = lc;
    out[4] = 0.0f;
    out[5] = nfg / fmaxf(acc[4], 1.0f);
  }
}

// ---------- launch ----------

extern "C" void kernel_launch(void* const* d_in, const int* in_sizes, int n_in,
                              void* d_out, int out_size, void* d_ws, size_t ws_size,
                              hipStream_t stream) {
  const float* o8     = (const float*)d_in[0];
  const float* o16    = (const float*)d_in[1];
  const float* o32    = (const float*)d_in[2];
  const float* labels = (const float*)d_in[3];
  float* out = (float*)d_out;

  char* w = (char*)d_ws;
  float* rec8 = (float*)w; w += (size_t)BB*AA*8*sizeof(float);
  float* L1p  = (float*)w; w += (size_t)BB*NCLS*AA*sizeof(float);
  float* L2p  = (float*)w; w += (size_t)BB*NCLS*AA*sizeof(float);
  int* cand   = (int*)w;   w += (size_t)BB*AA*sizeof(int);
  int* mcount = (int*)w;   w += (size_t)BB*AA*sizeof(int);
  int* mgsum  = (int*)w;   w += (size_t)BB*AA*sizeof(int);
  float* acc  = (float*)w; w += 256;
  float* grec = (float*)w; w += (size_t)BB*GG*GREC*sizeof(float);
  float* part_c = (float*)w; w += (size_t)BB*GG*SPLIT*TK*sizeof(float);
  int*   part_i = (int*)w;   w += (size_t)BB*GG*SPLIT*TK*sizeof(int);
  float* part_v = (float*)w; w += (size_t)BB*GG*SPLIT*TK*sizeof(float);

  // zero mcount+mgsum+acc (contiguous)
  hipMemsetAsync(mcount, 0, (size_t)BB*AA*sizeof(int)*2 + 256, stream);

  int nBA = BB*AA;  // 172032 = 672*256
  k_gt<<<2, 256, 0, stream>>>(labels, grec, acc);
  k_decode<<<nBA/256, 256, 0, stream>>>(o8, o16, o32, grec, rec8, L1p, L2p, cand);
  k_assign_part<<<BB*GG*SPLIT, 256, 0, stream>>>(rec8, grec, cand, L1p, L2p, part_c, part_i, part_v);
  k_merge<<<2, 256, 0, stream>>>(grec, part_c, part_i, part_v, mcount, mgsum);
  k_losses<<<nBA/256, 256, 0, stream>>>(o8, o16, o32, rec8, grec, cand, mcount, mgsum, L1p, L2p, acc);
  k_fin<<<1, 64, 0, stream>>>(acc, out);
}

// Round 3
// 253.930 us; speedup vs baseline: 1.6352x; 1.3362x over previous
//
#include <hip/hip_runtime.h>
#include <math.h>

#define NCLS 15
constexpr int BB = 8;
constexpr int GG = 60;
constexpr int AA = 21504;   // 128*128 + 64*64 + 32*32
constexpr int TK = 10;
constexpr int SPLIT = 4;
constexpr int SUB = AA / SPLIT;  // 5376
constexpr int GREC = 12;

// ---------- fast math (hw-native, ~1ulp; decisions robust vs threshold) ----------
__device__ __forceinline__ float frcp_(float x){ return __builtin_amdgcn_rcpf(x); }
__device__ __forceinline__ float flog2_(float x){ return __builtin_amdgcn_logf(x); }
__device__ __forceinline__ float fexp2_(float x){ return __builtin_amdgcn_exp2f(x); }
__device__ __forceinline__ float fsqrt_(float x){ return __builtin_amdgcn_sqrtf(x); }
#define LN2F  0.69314718055994531f
#define RLN2F 1.44269504088896341f
#define R2PIF 0.15915494309189535f
__device__ __forceinline__ float flog_(float x){ return flog2_(x) * LN2F; }
__device__ __forceinline__ float fexp_(float x){ return fexp2_(x * RLN2F); }
__device__ __forceinline__ float fsig_(float x){ return frcp_(1.0f + fexp2_(-x * RLN2F)); }

// ---------- helpers ----------

__device__ __forceinline__ void ageom(int a, float& xc, float& yc, float& rad) {
  if (a < 16384) {
    int i = a >> 7, j = a & 127;
    xc = (j + 0.5f) * 8.0f;  yc = (i + 0.5f) * 8.0f;  rad = 20.0f;
  } else if (a < 20480) {
    int l = a - 16384; int i = l >> 6, j = l & 63;
    xc = (j + 0.5f) * 16.0f; yc = (i + 0.5f) * 16.0f; rad = 40.0f;
  } else {
    int l = a - 20480; int i = l >> 5, j = l & 31;
    xc = (j + 0.5f) * 32.0f; yc = (i + 0.5f) * 32.0f; rad = 80.0f;
  }
}

__device__ __forceinline__ float prob_iou_fast(float x1,float y1,float a1,float b1,float c1,float d1,
                                               float x2,float y2,float a2,float b2,float c2,float d2) {
  float dx = x1 - x2, dy = y1 - y2;
  float Av = a1 + a2, Bv = b1 + b2, Cv = c1 + c2;
  float den = Av*Bv - Cv*Cv + 1e-8f;
  float q = 0.25f*(Av*dy*dy + Bv*dx*dx) - 0.5f*(Cv*dx*dy);
  float t12 = q * frcp_(den);
  float t3 = 0.5f*LN2F*(flog2_(den) - flog2_(4.0f*fsqrt_(d1*d2) + 1e-8f));
  float bd = t12 + t3;
  bd = fminf(fmaxf(bd, 1e-8f), 100.0f);
  float e = 1.0f - fexp2_(-bd * RLN2F);
  e = fminf(fmaxf(e, 0.0f), 1.0f);
  return 1.0f - fsqrt_(e);
}

// static-index insertion (register-resident; rule #20)
__device__ __forceinline__ void ins_cost(float (&cst)[TK], int (&cid)[TK], float c, int id) {
  bool ins = (c < cst[TK-1]) || (c == cst[TK-1] && id < cid[TK-1]);
  if (ins) {
    cst[TK-1] = c; cid[TK-1] = id;
    #pragma unroll
    for (int k = TK-1; k > 0; k--) {
      float tc = cst[k-1]; int ti = cid[k-1];
      bool sw = (cst[k] < tc) || (cst[k] == tc && cid[k] < ti);
      if (sw) { cst[k-1] = cst[k]; cid[k-1] = cid[k]; cst[k] = tc; cid[k] = ti; }
    }
  }
}

__device__ __forceinline__ void ins_vio(float (&vio)[TK], float v) {
  if (v > vio[TK-1]) {
    vio[TK-1] = v;
    #pragma unroll
    for (int k = TK-1; k > 0; k--) {
      float tv = vio[k-1];
      bool sw = vio[k] > tv;
      if (sw) { vio[k-1] = vio[k]; vio[k] = tv; }
    }
  }
}

__device__ __forceinline__ float blk_sum(float v, float* sw) {
  for (int o = 32; o > 0; o >>= 1) v += __shfl_down(v, o);
  int wid = threadIdx.x >> 6, lane = threadIdx.x & 63;
  __syncthreads();
  if (lane == 0) sw[wid] = v;
  __syncthreads();
  float rr = 0.0f;
  if (threadIdx.x == 0) rr = sw[0] + sw[1] + sw[2] + sw[3];
  return rr;
}

// ---------- kernels ----------

// gt record = [x,y,covA,covB,covC,covD,w,h,cls(int bits),valid,pad,pad]
__global__ void k_gt(const float* labels, float* grec, float* acc) {
  int t = blockIdx.x * 256 + threadIdx.x;
  if (t >= BB*GG) return;
  const float* L = labels + (size_t)t * 6;
  float s = 0.0f;
  for (int k = 0; k < 6; k++) s += L[k];
  float valid = (s > 0.0f) ? 1.0f : 0.0f;
  float x = L[1], y = L[2], w = L[3], h = L[4], ang = L[5];
  float w2 = w*w / 12.0f, h2 = h*h / 12.0f;
  float cc = cosf(ang), sn = sinf(ang);
  float cA = w2*cc*cc + h2*sn*sn;
  float cB = w2*sn*sn + h2*cc*cc;
  float cC = (w2 - h2)*cc*sn;
  float cD = fmaxf(cA*cB - cC*cC, 0.0f);
  float* gr = grec + (size_t)t * GREC;
  gr[0]=x; gr[1]=y; gr[2]=cA; gr[3]=cB; gr[4]=cC; gr[5]=cD;
  gr[6]=w; gr[7]=h; gr[8]=__int_as_float((int)L[0]); gr[9]=valid; gr[10]=0.0f; gr[11]=0.0f;
  if (valid != 0.0f) atomicAdd(&acc[4], 1.0f);
}

// decode + cand. rec8 = [x,y,cA,cB,cC,cD,S,obj]; Dp = [b][c][a] plane of (l1-l2)
__global__ __launch_bounds__(256) void k_decode(const float* o8, const float* o16, const float* o32,
                                                const float* grec,
                                                float* rec8, float* Dp, int* cand) {
  __shared__ float s_gx[GG], s_gy[GG], s_hw[GG], s_hh[GG], s_gv[GG];
  int t = blockIdx.x * 256 + threadIdx.x;
  int b = t / AA, a = t - b*AA;   // block fully within one b (AA%256==0)
  if (threadIdx.x < GG) {
    const float* gr = grec + (size_t)(b*GG + (int)threadIdx.x) * GREC;
    s_gx[threadIdx.x] = gr[0]; s_gy[threadIdx.x] = gr[1];
    s_hw[threadIdx.x] = 0.5f*gr[6]; s_hh[threadIdx.x] = 0.5f*gr[7];
    s_gv[threadIdx.x] = gr[9];
  }
  __syncthreads();

  const float* pb; int cs, i, j; float s;
  if (a < 16384)      { pb = o8  + ((size_t)b*21)*16384 + a;           cs = 16384; i = a>>7; j = a&127; s = 8.0f; }
  else if (a < 20480) { int l = a-16384; pb = o16 + ((size_t)b*21)*4096 + l; cs = 4096;  i = l>>6; j = l&63;  s = 16.0f; }
  else                { int l = a-20480; pb = o32 + ((size_t)b*21)*1024 + l; cs = 1024;  i = l>>5; j = l&31;  s = 32.0f; }

  float tx  = pb[0];
  float ty  = pb[(size_t)cs];
  float tw  = pb[(size_t)2*cs];
  float th  = pb[(size_t)3*cs];
  float ang = pb[(size_t)4*cs];
  float obj = pb[(size_t)5*cs];

  float x = (tx + (float)j) * s;
  float y = (ty + (float)i) * s;
  float w = fexp_(tw) * s;
  float h = fexp_(th) * s;

  float w2 = w*w / 12.0f, h2 = h*h / 12.0f;
  float rev = ang * R2PIF;
  float cc = __builtin_amdgcn_cosf(rev), sn = __builtin_amdgcn_sinf(rev);
  float cA = w2*cc*cc + h2*sn*sn;
  float cB = w2*sn*sn + h2*cc*cc;
  float cC = (w2 - h2)*cc*sn;
  float cD = fmaxf(cA*cB - cC*cC, 0.0f);

  float sobj = fsig_(obj);
  float S = 0.0f;
  float* dpb = Dp + (size_t)b*NCLS*AA + a;
  #pragma unroll
  for (int c = 0; c < NCLS; c++) {
    float xl = pb[(size_t)(6+c)*cs];
    float p  = fsqrt_(fsig_(xl) * sobj);
    p = fminf(fmaxf(p, 1e-7f), 1.0f - 1e-7f);
    float l1 = flog_(1.0f - p);
    float l2 = flog_(p);
    S -= l1;
    dpb[(size_t)c*AA] = l1 - l2;
  }
  float4* r4 = (float4*)(rec8 + (size_t)t * 8);
  r4[0] = make_float4(x, y, cA, cB);
  r4[1] = make_float4(cC, cD, S, obj);

  // cand = OR over g of (in_box | in_ctr)
  float xc = (j + 0.5f) * s, yc = (i + 0.5f) * s, rad = 2.5f * s;
  int cf = 0;
  for (int g = 0; g < GG; g++) {
    if (s_gv[g] != 0.0f) {
      float dxx = fabsf(xc - s_gx[g]), dyy = fabsf(yc - s_gy[g]);
      if (((dxx < s_hw[g]) && (dyy < s_hh[g])) || ((dxx < rad) && (dyy < rad))) { cf = 1; break; }
    }
  }
  cand[t] = cf;
}

// one block per (b,g,split): partial top-10 cost list + top-10 iou list.
// !cand pairs: provably never in top-dyn_k (every valid gt has >=16 cand anchors
// with cost < 1.1e5 while !cand cost >= ~1e6) -> full skip except vio(0).
__global__ __launch_bounds__(256) void k_assign_part(const float* rec8, const float* grec, const int* cand,
                                                     const float* Dp,
                                                     float* part_c, int* part_i, float* part_v) {
  int blk = blockIdx.x;
  int bg = blk / SPLIT, sp = blk - bg*SPLIT;
  int b = bg / GG;
  const float* gr = grec + (size_t)bg * GREC;
  if (gr[9] == 0.0f) return;  // dyn_k = 0, merge skips too

  float gx = gr[0], gy = gr[1], gA = gr[2], gB = gr[3], gC = gr[4], gD = gr[5];
  float hw = 0.5f*gr[6], hh = 0.5f*gr[7];
  int gcls = __float_as_int(gr[8]);

  __shared__ int s_nboth;
  if (threadIdx.x == 0) s_nboth = 0;
  __syncthreads();

  float cst[TK]; int cid[TK]; float vio[TK];
  #pragma unroll
  for (int k = 0; k < TK; k++) { cst[k] = 3.4e38f; cid[k] = 0x7fffffff; vio[k] = -1.0f; }

  const float* recb = rec8 + (size_t)b * AA * 8;
  const int*  candb = cand + (size_t)b * AA;
  const float* dpp  = Dp + ((size_t)b*NCLS + gcls)*AA;

  int a0 = sp * SUB;
  for (int a = a0 + (int)threadIdx.x; a < a0 + SUB; a += 256) {
    int cd = candb[a];
    if (!cd) {
      if (vio[TK-1] < 0.0f) ins_vio(vio, 0.0f);
      continue;
    }
    const float4* r4 = (const float4*)(recb + (size_t)a * 8);
    float4 v0 = r4[0], v1 = r4[1];
    float iou = prob_iou_fast(gx,gy,gA,gB,gC,gD, v0.x,v0.y,v0.z,v0.w,v1.x,v1.y);
    if (iou > vio[TK-1]) ins_vio(vio, iou);

    float xc, yc, rad; ageom(a, xc, yc, rad);
    float dx = fabsf(xc - gx), dy = fabsf(yc - gy);
    bool both = (dx < hw) && (dy < hh) && (dx < rad) && (dy < rad);
    int nb = *((volatile int*)&s_nboth);
    if (!both && nb >= TK) continue;   // block already has 10 both-pairs (cost<425 << 1e5)

    float cost = (v1.z + dpp[a]) + 3.0f * (-flog_(iou + 1e-8f));
    if (!both) cost += 1e5f;
    ins_cost(cst, cid, cost, a);
    if (both) atomicAdd(&s_nboth, 1);
  }

  // block tree-merge (128-row LDS staging keeps LDS at 15.4KB -> 8 blocks/CU)
  __shared__ float sh_c[128*TK];
  __shared__ int   sh_i[128*TK];
  __shared__ float sh_v[128*TK];
  int tid = threadIdx.x;
  for (int step = 128; step >= 1; step >>= 1) {
    if (tid >= step && tid < (step << 1)) {
      int base = (tid - step) * TK;
      #pragma unroll
      for (int k = 0; k < TK; k++) { sh_c[base+k]=cst[k]; sh_i[base+k]=cid[k]; sh_v[base+k]=vio[k]; }
    }
    __syncthreads();
    if (tid < step) {
      int base = tid * TK;
      float nc[TK]; int ni[TK]; float nv[TK];
      int pi = 0, pj = 0;
      #pragma unroll
      for (int k = 0; k < TK; k++) {
        float ca = cst[pi]; int ia = cid[pi];
        float cb = sh_c[base+pj]; int ib = sh_i[base+pj];
        bool ta = (ca < cb) || (ca == cb && ia < ib);
        nc[k] = ta ? ca : cb; ni[k] = ta ? ia : ib;
        pi += ta ? 1 : 0; pj += ta ? 0 : 1;
      }
      int qi = 0, qj = 0;
      #pragma unroll
      for (int k = 0; k < TK; k++) {
        float va = vio[qi], vb = sh_v[base+qj];
        bool ta = va >= vb;
        nv[k] = ta ? va : vb;
        qi += ta ? 1 : 0; qj += ta ? 0 : 1;
      }
      #pragma unroll
      for (int k = 0; k < TK; k++) { cst[k] = nc[k]; cid[k] = ni[k]; vio[k] = nv[k]; }
    }
    __syncthreads();
  }

  if (tid == 0) {
    float* pc = part_c + (size_t)blk * TK;
    int*   pi = part_i + (size_t)blk * TK;
    float* pv = part_v + (size_t)blk * TK;
    #pragma unroll
    for (int k = 0; k < TK; k++) { pc[k] = cst[k]; pi[k] = cid[k]; pv[k] = vio[k]; }
  }
}

// merge SPLIT partial lists per (b,g): dyn_k + match atomics
__global__ void k_merge(const float* grec, const float* part_c, const int* part_i, const float* part_v,
                        int* mcount, int* mgsum) {
  int t = blockIdx.x * 256 + threadIdx.x;
  if (t >= BB*GG) return;
  const float* gr = grec + (size_t)t * GREC;
  if (gr[9] == 0.0f) return;
  int b = t / GG, g = t - b*GG;
  const float* pc = part_c + (size_t)t * SPLIT * TK;
  const int*   pi = part_i + (size_t)t * SPLIT * TK;
  const float* pv = part_v + (size_t)t * SPLIT * TK;

  // top-10 iou sum (descending merge of 4 sorted lists)
  int q0=0,q1=0,q2=0,q3=0;
  float vs = 0.0f;
  for (int k = 0; k < TK; k++) {
    float b0 = pv[0*TK+q0], b1 = pv[1*TK+q1], b2 = pv[2*TK+q2], b3 = pv[3*TK+q3];
    int sel = 0; float bv = b0;
    if (b1 > bv) { bv = b1; sel = 1; }
    if (b2 > bv) { bv = b2; sel = 2; }
    if (b3 > bv) { bv = b3; sel = 3; }
    vs += bv;
    if (sel==0) q0++; else if (sel==1) q1++; else if (sel==2) q2++; else q3++;
  }
  int dynk = (int)vs;
  if (dynk < 1) dynk = 1;
  if (dynk > TK) dynk = TK;

  int* mc = mcount + (size_t)b * AA;
  int* mg = mgsum  + (size_t)b * AA;
  int p0=0,p1=0,p2=0,p3=0;
  for (int k = 0; k < dynk; k++) {
    float c0 = pc[0*TK+p0]; int i0 = pi[0*TK+p0];
    float c1 = pc[1*TK+p1]; int i1 = pi[1*TK+p1];
    float c2 = pc[2*TK+p2]; int i2 = pi[2*TK+p2];
    float c3 = pc[3*TK+p3]; int i3 = pi[3*TK+p3];
    int sel = 0; float bc = c0; int bi = i0;
    if (c1 < bc || (c1 == bc && i1 < bi)) { bc = c1; bi = i1; sel = 1; }
    if (c2 < bc || (c2 == bc && i2 < bi)) { bc = c2; bi = i2; sel = 2; }
    if (c3 < bc || (c3 == bc && i3 < bi)) { bc = c3; bi = i3; sel = 3; }
    if (sel==0) p0++; else if (sel==1) p1++; else if (sel==2) p2++; else p3++;
    atomicAdd(&mc[bi], 1);
    atomicAdd(&mg[bi], g);
  }
}

// per-anchor conflict resolution + loss contributions
__global__ __launch_bounds__(256) void k_losses(const float* o8, const float* o16, const float* o32,
                                                const float* rec8, const float* grec,
                                                const int* cand, const int* mcount, const int* mgsum,
                                                const float* Dp, float* acc) {
  int t = blockIdx.x * 256 + threadIdx.x;
  int b = t / AA, a = t - b*AA;
  const float4* r4 = (const float4*)(rec8 + (size_t)t * 8);
  float4 v0 = r4[0], v1 = r4[1];
  int cnt = mcount[t];
  float fg = (cnt > 0) ? 1.0f : 0.0f;
  float obj = v1.w;
  float eo = fexp2_(-fabsf(obj) * RLN2F);
  float lobj = fmaxf(obj, 0.0f) - obj*fg + flog_(1.0f + eo);
  float liou = 0.0f, lcls = 0.0f;

  if (cnt > 0) {
    int gstar;
    if (cnt == 1) {
      gstar = mgsum[t];
    } else {
      float xc, yc, rad; ageom(a, xc, yc, rad);
      int cd = cand[t];
      float best = 3.4e38f; gstar = 0;
      for (int g = 0; g < GG; g++) {
        const float* gg = grec + (size_t)(b*GG + g) * GREC;
        float valid = gg[9];
        float iou = prob_iou_fast(gg[0],gg[1],gg[2],gg[3],gg[4],gg[5],
                                  v0.x,v0.y,v0.z,v0.w,v1.x,v1.y);
        if (valid == 0.0f) iou = 0.0f;
        int gcls = __float_as_int(gg[8]);
        float cost = (v1.z + Dp[((size_t)b*NCLS + gcls)*AA + a]) + 3.0f * (-flog_(iou + 1e-8f));
        float dx = fabsf(xc - gg[0]), dy = fabsf(yc - gg[1]);
        bool vb = (valid != 0.0f);
        bool ib = (dx < 0.5f*gg[6]) && (dy < 0.5f*gg[7]) && vb;
        bool ic = (dx < rad) && (dy < rad) && vb;
        if (!(ib && ic)) cost += 1e5f;
        if (!cd)         cost += 1e6f;
        if (!vb)         cost += 1e9f;
        if (cost < best) { best = cost; gstar = g; }
      }
    }
    const float* gg = grec + (size_t)(b*GG + gstar) * GREC;
    float I = prob_iou_fast(gg[0],gg[1],gg[2],gg[3],gg[4],gg[5],
                            v0.x,v0.y,v0.z,v0.w,v1.x,v1.y);
    if (gg[9] == 0.0f) I = 0.0f;
    liou = 1.0f - I;
    int gcls = __float_as_int(gg[8]);

    const float* pb; int cs;
    if (a < 16384)      { pb = o8  + ((size_t)b*21)*16384 + a;           cs = 16384; }
    else if (a < 20480) { pb = o16 + ((size_t)b*21)*4096 + (a-16384);    cs = 4096;  }
    else                { pb = o32 + ((size_t)b*21)*1024 + (a-20480);    cs = 1024;  }
    #pragma unroll
    for (int c = 0; c < NCLS; c++) {
      float xl = pb[(size_t)(6+c)*cs];
      float tgt = (c == gcls) ? I : 0.0f;
      float ex = fexp2_(-fabsf(xl) * RLN2F);
      lcls += fmaxf(xl, 0.0f) - xl*tgt + flog_(1.0f + ex);
    }
  }

  __shared__ float sw[4];
  float v;
  v = blk_sum(fg,   sw); if (threadIdx.x == 0) atomicAdd(&acc[0], v);
  v = blk_sum(liou, sw); if (threadIdx.x == 0) atomicAdd(&acc[1], v);
  v = blk_sum(lobj, sw); if (threadIdx.x == 0) atomicAdd(&acc[2], v);
  v = blk_sum(lcls, sw); if (threadIdx.x == 0) atomicAdd(&acc[3], v);
}

__global__ void k_fin(const float* acc, float* out) {
  if (threadIdx.x == 0 && blockIdx.x == 0) {
    float nfg = acc[0];
    float nf  = fmaxf(nfg, 1.0f);
    float li = acc[1] / nf;
    float lo = acc[2] / nf;
    float lc = acc[3] / nf;
    float l5 = 5.0f * li;
    out[0] = l5 + lo + lc;
    out[1] = l5;
    out[2] = lo;
    out[3] = lc;
    out[4] = 0.0f;
    out[5] = nfg / fmaxf(acc[4], 1.0f);
  }
}

// ---------- launch ----------

extern "C" void kernel_launch(void* const* d_in, const int* in_sizes, int n_in,
                              void* d_out, int out_size, void* d_ws, size_t ws_size,
                              hipStream_t stream) {
  const float* o8     = (const float*)d_in[0];
  const float* o16    = (const float*)d_in[1];
  const float* o32    = (const float*)d_in[2];
  const float* labels = (const float*)d_in[3];
  float* out = (float*)d_out;

  char* w = (char*)d_ws;
  float* rec8 = (float*)w; w += (size_t)BB*AA*8*sizeof(float);
  float* Dp   = (float*)w; w += (size_t)BB*NCLS*AA*sizeof(float);
  int* cand   = (int*)w;   w += (size_t)BB*AA*sizeof(int);
  int* mcount = (int*)w;   w += (size_t)BB*AA*sizeof(int);
  int* mgsum  = (int*)w;   w += (size_t)BB*AA*sizeof(int);
  float* acc  = (float*)w; w += 256;
  float* grec = (float*)w; w += (size_t)BB*GG*GREC*sizeof(float);
  float* part_c = (float*)w; w += (size_t)BB*GG*SPLIT*TK*sizeof(float);
  int*   part_i = (int*)w;   w += (size_t)BB*GG*SPLIT*TK*sizeof(int);
  float* part_v = (float*)w; w += (size_t)BB*GG*SPLIT*TK*sizeof(float);

  // zero mcount+mgsum+acc (contiguous)
  hipMemsetAsync(mcount, 0, (size_t)BB*AA*sizeof(int)*2 + 256, stream);

  int nBA = BB*AA;  // 172032 = 672*256
  k_gt<<<2, 256, 0, stream>>>(labels, grec, acc);
  k_decode<<<nBA/256, 256, 0, stream>>>(o8, o16, o32, grec, rec8, Dp, cand);
  k_assign_part<<<BB*GG*SPLIT, 256, 0, stream>>>(rec8, grec, cand, Dp, part_c, part_i, part_v);
  k_merge<<<2, 256, 0, stream>>>(grec, part_c, part_i, part_v, mcount, mgsum);
  k_losses<<<nBA/256, 256, 0, stream>>>(o8, o16, o32, rec8, grec, cand, mcount, mgsum, Dp, acc);
  k_fin<<<1, 64, 0, stream>>>(acc, out);
}

// Round 4
// 248.469 us; speedup vs baseline: 1.6711x; 1.0220x over previous
//
#include <hip/hip_runtime.h>
#include <math.h>

#define NCLS 15
constexpr int BB = 8;
constexpr int GG = 60;
constexpr int AA = 21504;   // 128*128 + 64*64 + 32*32
constexpr int TK = 10;
constexpr int SPLIT = 4;
constexpr int GREC = 12;

// ---------- fast math (hw-native, ~1ulp) ----------
__device__ __forceinline__ float frcp_(float x){ return __builtin_amdgcn_rcpf(x); }
__device__ __forceinline__ float flog2_(float x){ return __builtin_amdgcn_logf(x); }
__device__ __forceinline__ float fexp2_(float x){ return __builtin_amdgcn_exp2f(x); }
__device__ __forceinline__ float fsqrt_(float x){ return __builtin_amdgcn_sqrtf(x); }
#define LN2F  0.69314718055994531f
#define RLN2F 1.44269504088896341f
#define R2PIF 0.15915494309189535f
__device__ __forceinline__ float flog_(float x){ return flog2_(x) * LN2F; }
__device__ __forceinline__ float fexp_(float x){ return fexp2_(x * RLN2F); }
__device__ __forceinline__ float fsig_(float x){ return frcp_(1.0f + fexp2_(-x * RLN2F)); }

// ---------- helpers ----------

__device__ __forceinline__ void ageom(int a, float& xc, float& yc, float& rad) {
  if (a < 16384) {
    int i = a >> 7, j = a & 127;
    xc = (j + 0.5f) * 8.0f;  yc = (i + 0.5f) * 8.0f;  rad = 20.0f;
  } else if (a < 20480) {
    int l = a - 16384; int i = l >> 6, j = l & 63;
    xc = (j + 0.5f) * 16.0f; yc = (i + 0.5f) * 16.0f; rad = 40.0f;
  } else {
    int l = a - 20480; int i = l >> 5, j = l & 31;
    xc = (j + 0.5f) * 32.0f; yc = (i + 0.5f) * 32.0f; rad = 80.0f;
  }
}

__device__ __forceinline__ float prob_iou_fast(float x1,float y1,float a1,float b1,float c1,float d1,
                                               float x2,float y2,float a2,float b2,float c2,float d2) {
  float dx = x1 - x2, dy = y1 - y2;
  float Av = a1 + a2, Bv = b1 + b2, Cv = c1 + c2;
  float den = Av*Bv - Cv*Cv + 1e-8f;
  float q = 0.25f*(Av*dy*dy + Bv*dx*dx) - 0.5f*(Cv*dx*dy);
  float t12 = q * frcp_(den);
  float t3 = 0.5f*LN2F*(flog2_(den) - flog2_(4.0f*fsqrt_(d1*d2) + 1e-8f));
  float bd = t12 + t3;
  bd = fminf(fmaxf(bd, 1e-8f), 100.0f);
  float e = 1.0f - fexp2_(-bd * RLN2F);
  e = fminf(fmaxf(e, 0.0f), 1.0f);
  return 1.0f - fsqrt_(e);
}

// static-index insertion (register-resident; rule #20)
__device__ __forceinline__ void ins_cost(float (&cst)[TK], int (&cid)[TK], float c, int id) {
  bool ins = (c < cst[TK-1]) || (c == cst[TK-1] && id < cid[TK-1]);
  if (ins) {
    cst[TK-1] = c; cid[TK-1] = id;
    #pragma unroll
    for (int k = TK-1; k > 0; k--) {
      float tc = cst[k-1]; int ti = cid[k-1];
      bool sw = (cst[k] < tc) || (cst[k] == tc && cid[k] < ti);
      if (sw) { cst[k-1] = cst[k]; cid[k-1] = cid[k]; cst[k] = tc; cid[k] = ti; }
    }
  }
}

__device__ __forceinline__ void ins_vio(float (&vio)[TK], float v) {
  if (v > vio[TK-1]) {
    vio[TK-1] = v;
    #pragma unroll
    for (int k = TK-1; k > 0; k--) {
      float tv = vio[k-1];
      bool sw = vio[k] > tv;
      if (sw) { vio[k-1] = vio[k]; vio[k] = tv; }
    }
  }
}

__device__ __forceinline__ float blk_sum(float v, float* sw) {
  for (int o = 32; o > 0; o >>= 1) v += __shfl_down(v, o);
  int wid = threadIdx.x >> 6, lane = threadIdx.x & 63;
  __syncthreads();
  if (lane == 0) sw[wid] = v;
  __syncthreads();
  float rr = 0.0f;
  if (threadIdx.x == 0) rr = sw[0] + sw[1] + sw[2] + sw[3];
  return rr;
}

// ---------- kernels ----------

// one block per (b,g): thread0 builds gt record; all threads rasterize cand cells.
// Per-cell predicate is BIT-IDENTICAL to the reference's per-anchor test; the
// bounding rects are conservative (+/-1 cell guard), so cand matches exactly.
__global__ __launch_bounds__(256) void k_gtraster(const float* labels, float* grec, float* acc, int* cand) {
  int bg = blockIdx.x;
  int b = bg / GG;
  __shared__ float sgx, sgy, shw, shh;
  __shared__ int svalid;
  if (threadIdx.x == 0) {
    const float* L = labels + (size_t)bg * 6;
    float ssum = 0.0f;
    for (int k = 0; k < 6; k++) ssum += L[k];
    float valid = (ssum > 0.0f) ? 1.0f : 0.0f;
    float x = L[1], y = L[2], w = L[3], h = L[4], ang = L[5];
    float w2 = w*w/12.0f, h2 = h*h/12.0f;
    float cc = cosf(ang), sn = sinf(ang);
    float cA = w2*cc*cc + h2*sn*sn;
    float cB = w2*sn*sn + h2*cc*cc;
    float cC = (w2-h2)*cc*sn;
    float cD = fmaxf(cA*cB - cC*cC, 0.0f);
    float* gr = grec + (size_t)bg * GREC;
    gr[0]=x; gr[1]=y; gr[2]=cA; gr[3]=cB; gr[4]=cC; gr[5]=cD;
    gr[6]=w; gr[7]=h; gr[8]=__int_as_float((int)L[0]); gr[9]=valid; gr[10]=0.0f; gr[11]=0.0f;
    if (valid != 0.0f) atomicAdd(&acc[4], 1.0f);
    sgx = x; sgy = y; shw = 0.5f*w; shh = 0.5f*h;
    svalid = (valid != 0.0f) ? 1 : 0;
  }
  __syncthreads();
  if (!svalid) return;
  float gx = sgx, gy = sgy, hw = shw, hh = shh;
  int* cb = cand + (size_t)b * AA;
  int tid = threadIdx.x;
  #pragma unroll
  for (int lvl = 0; lvl < 3; lvl++) {
    const int   W    = (lvl==0)?128:((lvl==1)?64:32);
    const int   base = (lvl==0)?0:((lvl==1)?16384:20480);
    const float s    = (lvl==0)?8.0f:((lvl==1)?16.0f:32.0f);
    const float invs = (lvl==0)?0.125f:((lvl==1)?0.0625f:0.03125f);
    const float rad  = 2.5f*s;
    #pragma unroll
    for (int rc = 0; rc < 2; rc++) {
      float mx = rc ? rad : hw;
      float my = rc ? rad : hh;
      int jlo = (int)floorf((gx - mx)*invs - 0.5f) - 1; if (jlo < 0) jlo = 0;
      int jhi = (int)ceilf ((gx + mx)*invs - 0.5f) + 1; if (jhi > W-1) jhi = W-1;
      int ilo = (int)floorf((gy - my)*invs - 0.5f) - 1; if (ilo < 0) ilo = 0;
      int ihi = (int)ceilf ((gy + my)*invs - 0.5f) + 1; if (ihi > W-1) ihi = W-1;
      if (jhi < jlo || ihi < ilo) continue;
      int nw = jhi - jlo + 1;
      int tot = nw * (ihi - ilo + 1);
      for (int k = tid; k < tot; k += 256) {
        int q = k / nw;
        int ii = ilo + q;
        int jj = jlo + (k - q*nw);
        float dx = fabsf(((float)jj + 0.5f)*s - gx);
        float dy = fabsf(((float)ii + 0.5f)*s - gy);
        if (dx < mx && dy < my) cb[base + ii*W + jj] = 1;
      }
    }
  }
}

// decode + wave-compaction of cand indices.
// rec8 = [x,y,cA,cB,cC,cD,S,obj]; Dp = [b][c][a] plane of (l1-l2)
__global__ __launch_bounds__(256) void k_decode(const float* o8, const float* o16, const float* o32,
                                                float* rec8, float* Dp, const int* cand,
                                                int* ncand, int* clist) {
  int t = blockIdx.x * 256 + threadIdx.x;
  int b = t / AA, a = t - b*AA;

  const float* pb; int cs, i, j; float s;
  if (a < 16384)      { pb = o8  + ((size_t)b*21)*16384 + a;           cs = 16384; i = a>>7; j = a&127; s = 8.0f; }
  else if (a < 20480) { int l = a-16384; pb = o16 + ((size_t)b*21)*4096 + l; cs = 4096;  i = l>>6; j = l&63;  s = 16.0f; }
  else                { int l = a-20480; pb = o32 + ((size_t)b*21)*1024 + l; cs = 1024;  i = l>>5; j = l&31;  s = 32.0f; }

  float tx  = pb[0];
  float ty  = pb[(size_t)cs];
  float tw  = pb[(size_t)2*cs];
  float th  = pb[(size_t)3*cs];
  float ang = pb[(size_t)4*cs];
  float obj = pb[(size_t)5*cs];

  float x = (tx + (float)j) * s;
  float y = (ty + (float)i) * s;
  float w = fexp_(tw) * s;
  float h = fexp_(th) * s;

  float w2 = w*w / 12.0f, h2 = h*h / 12.0f;
  float rev = ang * R2PIF;
  float cc = __builtin_amdgcn_cosf(rev), sn = __builtin_amdgcn_sinf(rev);
  float cA = w2*cc*cc + h2*sn*sn;
  float cB = w2*sn*sn + h2*cc*cc;
  float cC = (w2 - h2)*cc*sn;
  float cD = fmaxf(cA*cB - cC*cC, 0.0f);

  float sobj = fsig_(obj);
  float S = 0.0f;
  float* dpb = Dp + (size_t)b*NCLS*AA + a;
  #pragma unroll
  for (int c = 0; c < NCLS; c++) {
    float xl = pb[(size_t)(6+c)*cs];
    float p  = fsqrt_(fsig_(xl) * sobj);
    p = fminf(fmaxf(p, 1e-7f), 1.0f - 1e-7f);
    float l1 = flog_(1.0f - p);
    float l2 = flog_(p);
    S -= l1;
    dpb[(size_t)c*AA] = l1 - l2;
  }
  float4* r4 = (float4*)(rec8 + (size_t)t * 8);
  r4[0] = make_float4(x, y, cA, cB);
  r4[1] = make_float4(cC, cD, S, obj);

  // wave-aggregated compaction of cand anchors
  int pred = cand[t];
  unsigned long long m = __ballot(pred != 0);
  if (m) {
    int lane = threadIdx.x & 63;
    int base = 0;
    if (lane == 0) base = atomicAdd(&ncand[b], (int)__popcll(m));
    base = __shfl(base, 0);
    if (pred) {
      int off = (int)__popcll(m & ((1ull << lane) - 1ull));
      clist[(size_t)b*AA + base + off] = a;
    }
  }
}

// one block per (b,g,split): strided over the compacted cand list.
__global__ __launch_bounds__(256) void k_assign_part(const float* rec8, const float* grec,
                                                     const float* Dp, const int* ncand, const int* clist,
                                                     float* part_c, int* part_i, float* part_v) {
  int blk = blockIdx.x;
  int bg = blk / SPLIT, sp = blk - bg*SPLIT;
  int b = bg / GG;
  const float* gr = grec + (size_t)bg * GREC;
  if (gr[9] == 0.0f) return;  // dyn_k = 0, merge skips too

  float gx = gr[0], gy = gr[1], gA = gr[2], gB = gr[3], gC = gr[4], gD = gr[5];
  float hw = 0.5f*gr[6], hh = 0.5f*gr[7];
  int gcls = __float_as_int(gr[8]);

  __shared__ int s_nboth;
  if (threadIdx.x == 0) s_nboth = 0;
  __syncthreads();

  float cst[TK]; int cid[TK]; float vio[TK];
  #pragma unroll
  for (int k = 0; k < TK; k++) { cst[k] = 3.4e38f; cid[k] = 0x7fffffff; vio[k] = -1.0f; }

  const float* recb = rec8 + (size_t)b * AA * 8;
  const float* dpp  = Dp + ((size_t)b*NCLS + gcls)*AA;
  const int*   cl   = clist + (size_t)b * AA;
  int n = ncand[b];

  for (int k = sp*256 + (int)threadIdx.x; k < n; k += SPLIT*256) {
    int a = cl[k];
    const float4* r4 = (const float4*)(recb + (size_t)a * 8);
    float4 v0 = r4[0], v1 = r4[1];
    float iou = prob_iou_fast(gx,gy,gA,gB,gC,gD, v0.x,v0.y,v0.z,v0.w,v1.x,v1.y);
    if (iou > vio[TK-1]) ins_vio(vio, iou);

    float xc, yc, rad; ageom(a, xc, yc, rad);
    float dx = fabsf(xc - gx), dy = fabsf(yc - gy);
    bool both = (dx < hw) && (dy < hh) && (dx < rad) && (dy < rad);
    int nb = *((volatile int*)&s_nboth);
    if (!both && nb >= TK) continue;   // 10 both-pairs already: cost<425 << 1e5

    float cost = (v1.z + dpp[a]) + 3.0f * (-flog_(iou + 1e-8f));
    if (!both) cost += 1e5f;
    ins_cost(cst, cid, cost, a);
    if (both) atomicAdd(&s_nboth, 1);
  }

  // block tree-merge (128-row LDS staging)
  __shared__ float sh_c[128*TK];
  __shared__ int   sh_i[128*TK];
  __shared__ float sh_v[128*TK];
  int tid = threadIdx.x;
  for (int step = 128; step >= 1; step >>= 1) {
    if (tid >= step && tid < (step << 1)) {
      int base = (tid - step) * TK;
      #pragma unroll
      for (int k = 0; k < TK; k++) { sh_c[base+k]=cst[k]; sh_i[base+k]=cid[k]; sh_v[base+k]=vio[k]; }
    }
    __syncthreads();
    if (tid < step) {
      int base = tid * TK;
      float nc[TK]; int ni[TK]; float nv[TK];
      int pi = 0, pj = 0;
      #pragma unroll
      for (int k = 0; k < TK; k++) {
        float ca = cst[pi]; int ia = cid[pi];
        float cb = sh_c[base+pj]; int ib = sh_i[base+pj];
        bool ta = (ca < cb) || (ca == cb && ia < ib);
        nc[k] = ta ? ca : cb; ni[k] = ta ? ia : ib;
        pi += ta ? 1 : 0; pj += ta ? 0 : 1;
      }
      int qi = 0, qj = 0;
      #pragma unroll
      for (int k = 0; k < TK; k++) {
        float va = vio[qi], vb = sh_v[base+qj];
        bool ta = va >= vb;
        nv[k] = ta ? va : vb;
        qi += ta ? 1 : 0; qj += ta ? 0 : 1;
      }
      #pragma unroll
      for (int k = 0; k < TK; k++) { cst[k] = nc[k]; cid[k] = ni[k]; vio[k] = nv[k]; }
    }
    __syncthreads();
  }

  if (tid == 0) {
    float* pc = part_c + (size_t)blk * TK;
    int*   pi = part_i + (size_t)blk * TK;
    float* pv = part_v + (size_t)blk * TK;
    #pragma unroll
    for (int k = 0; k < TK; k++) { pc[k] = cst[k]; pi[k] = cid[k]; pv[k] = vio[k]; }
  }
}

// merge SPLIT partial lists per (b,g): dyn_k + match atomics.
// vio entries clamped at 0: the >=10 non-cand anchors contribute exact zeros.
__global__ void k_merge(const float* grec, const float* part_c, const int* part_i, const float* part_v,
                        int* mcount, int* mgsum) {
  int t = blockIdx.x * 256 + threadIdx.x;
  if (t >= BB*GG) return;
  const float* gr = grec + (size_t)t * GREC;
  if (gr[9] == 0.0f) return;
  int b = t / GG, g = t - b*GG;
  const float* pc = part_c + (size_t)t * SPLIT * TK;
  const int*   pi = part_i + (size_t)t * SPLIT * TK;
  const float* pv = part_v + (size_t)t * SPLIT * TK;

  int q0=0,q1=0,q2=0,q3=0;
  float vs = 0.0f;
  for (int k = 0; k < TK; k++) {
    float b0 = pv[0*TK+q0], b1 = pv[1*TK+q1], b2 = pv[2*TK+q2], b3 = pv[3*TK+q3];
    int sel = 0; float bv = b0;
    if (b1 > bv) { bv = b1; sel = 1; }
    if (b2 > bv) { bv = b2; sel = 2; }
    if (b3 > bv) { bv = b3; sel = 3; }
    vs += fmaxf(bv, 0.0f);
    if (sel==0) q0++; else if (sel==1) q1++; else if (sel==2) q2++; else q3++;
  }
  int dynk = (int)vs;
  if (dynk < 1) dynk = 1;
  if (dynk > TK) dynk = TK;

  int* mc = mcount + (size_t)b * AA;
  int* mg = mgsum  + (size_t)b * AA;
  int p0=0,p1=0,p2=0,p3=0;
  for (int k = 0; k < dynk; k++) {
    float c0 = pc[0*TK+p0]; int i0 = pi[0*TK+p0];
    float c1 = pc[1*TK+p1]; int i1 = pi[1*TK+p1];
    float c2 = pc[2*TK+p2]; int i2 = pi[2*TK+p2];
    float c3 = pc[3*TK+p3]; int i3 = pi[3*TK+p3];
    int sel = 0; float bc = c0; int bi = i0;
    if (c1 < bc || (c1 == bc && i1 < bi)) { bc = c1; bi = i1; sel = 1; }
    if (c2 < bc || (c2 == bc && i2 < bi)) { bc = c2; bi = i2; sel = 2; }
    if (c3 < bc || (c3 == bc && i3 < bi)) { bc = c3; bi = i3; sel = 3; }
    if (sel==0) p0++; else if (sel==1) p1++; else if (sel==2) p2++; else p3++;
    atomicAdd(&mc[bi], 1);
    atomicAdd(&mg[bi], g);
  }
}

// per-anchor conflict resolution + loss contributions
__global__ __launch_bounds__(256) void k_losses(const float* o8, const float* o16, const float* o32,
                                                const float* rec8, const float* grec,
                                                const int* cand, const int* mcount, const int* mgsum,
                                                const float* Dp, float* acc) {
  int t = blockIdx.x * 256 + threadIdx.x;
  int b = t / AA, a = t - b*AA;
  const float4* r4 = (const float4*)(rec8 + (size_t)t * 8);
  float4 v1 = r4[1];
  int cnt = mcount[t];
  float fg = (cnt > 0) ? 1.0f : 0.0f;
  float obj = v1.w;
  float eo = fexp2_(-fabsf(obj) * RLN2F);
  float lobj = fmaxf(obj, 0.0f) - obj*fg + flog_(1.0f + eo);
  float liou = 0.0f, lcls = 0.0f;

  if (cnt > 0) {
    float4 v0 = r4[0];
    int gstar;
    if (cnt == 1) {
      gstar = mgsum[t];
    } else {
      float xc, yc, rad; ageom(a, xc, yc, rad);
      int cd = cand[t];
      float best = 3.4e38f; gstar = 0;
      for (int g = 0; g < GG; g++) {
        const float* gg = grec + (size_t)(b*GG + g) * GREC;
        float valid = gg[9];
        float iou = prob_iou_fast(gg[0],gg[1],gg[2],gg[3],gg[4],gg[5],
                                  v0.x,v0.y,v0.z,v0.w,v1.x,v1.y);
        if (valid == 0.0f) iou = 0.0f;
        int gcls = __float_as_int(gg[8]);
        float cost = (v1.z + Dp[((size_t)b*NCLS + gcls)*AA + a]) + 3.0f * (-flog_(iou + 1e-8f));
        float dx = fabsf(xc - gg[0]), dy = fabsf(yc - gg[1]);
        bool vb = (valid != 0.0f);
        bool ib = (dx < 0.5f*gg[6]) && (dy < 0.5f*gg[7]) && vb;
        bool ic = (dx < rad) && (dy < rad) && vb;
        if (!(ib && ic)) cost += 1e5f;
        if (!cd)         cost += 1e6f;
        if (!vb)         cost += 1e9f;
        if (cost < best) { best = cost; gstar = g; }
      }
    }
    const float* gg = grec + (size_t)(b*GG + gstar) * GREC;
    float I = prob_iou_fast(gg[0],gg[1],gg[2],gg[3],gg[4],gg[5],
                            v0.x,v0.y,v0.z,v0.w,v1.x,v1.y);
    if (gg[9] == 0.0f) I = 0.0f;
    liou = 1.0f - I;
    int gcls = __float_as_int(gg[8]);

    const float* pb; int cs;
    if (a < 16384)      { pb = o8  + ((size_t)b*21)*16384 + a;           cs = 16384; }
    else if (a < 20480) { pb = o16 + ((size_t)b*21)*4096 + (a-16384);    cs = 4096;  }
    else                { pb = o32 + ((size_t)b*21)*1024 + (a-20480);    cs = 1024;  }
    #pragma unroll
    for (int c = 0; c < NCLS; c++) {
      float xl = pb[(size_t)(6+c)*cs];
      float tgt = (c == gcls) ? I : 0.0f;
      float ex = fexp2_(-fabsf(xl) * RLN2F);
      lcls += fmaxf(xl, 0.0f) - xl*tgt + flog_(1.0f + ex);
    }
  }

  __shared__ float sw[4];
  float v;
  v = blk_sum(fg,   sw); if (threadIdx.x == 0) atomicAdd(&acc[0], v);
  v = blk_sum(liou, sw); if (threadIdx.x == 0) atomicAdd(&acc[1], v);
  v = blk_sum(lobj, sw); if (threadIdx.x == 0) atomicAdd(&acc[2], v);
  v = blk_sum(lcls, sw); if (threadIdx.x == 0) atomicAdd(&acc[3], v);
}

__global__ void k_fin(const float* acc, float* out) {
  if (threadIdx.x == 0 && blockIdx.x == 0) {
    float nfg = acc[0];
    float nf  = fmaxf(nfg, 1.0f);
    float li = acc[1] / nf;
    float lo = acc[2] / nf;
    float lc = acc[3] / nf;
    float l5 = 5.0f * li;
    out[0] = l5 + lo + lc;
    out[1] = l5;
    out[2] = lo;
    out[3] = lc;
    out[4] = 0.0f;
    out[5] = nfg / fmaxf(acc[4], 1.0f);
  }
}

// ---------- launch ----------

extern "C" void kernel_launch(void* const* d_in, const int* in_sizes, int n_in,
                              void* d_out, int out_size, void* d_ws, size_t ws_size,
                              hipStream_t stream) {
  const float* o8     = (const float*)d_in[0];
  const float* o16    = (const float*)d_in[1];
  const float* o32    = (const float*)d_in[2];
  const float* labels = (const float*)d_in[3];
  float* out = (float*)d_out;

  char* w = (char*)d_ws;
  float* rec8 = (float*)w; w += (size_t)BB*AA*8*sizeof(float);
  float* Dp   = (float*)w; w += (size_t)BB*NCLS*AA*sizeof(float);
  int* clist  = (int*)w;   w += (size_t)BB*AA*sizeof(int);
  float* grec = (float*)w; w += (size_t)BB*GG*GREC*sizeof(float);
  float* part_c = (float*)w; w += (size_t)BB*GG*SPLIT*TK*sizeof(float);
  int*   part_i = (int*)w;   w += (size_t)BB*GG*SPLIT*TK*sizeof(int);
  float* part_v = (float*)w; w += (size_t)BB*GG*SPLIT*TK*sizeof(float);
  // zeroed region (contiguous): cand, mcount, mgsum, ncand, acc
  int* cand   = (int*)w;   w += (size_t)BB*AA*sizeof(int);
  int* mcount = (int*)w;   w += (size_t)BB*AA*sizeof(int);
  int* mgsum  = (int*)w;   w += (size_t)BB*AA*sizeof(int);
  int* ncand  = (int*)w;   w += 128;
  float* acc  = (float*)w; w += 256;

  size_t zbytes = (size_t)BB*AA*sizeof(int)*3 + 128 + 256;
  hipMemsetAsync(cand, 0, zbytes, stream);

  int nBA = BB*AA;  // 172032 = 672*256
  k_gtraster<<<BB*GG, 256, 0, stream>>>(labels, grec, acc, cand);
  k_decode<<<nBA/256, 256, 0, stream>>>(o8, o16, o32, rec8, Dp, cand, ncand, clist);
  k_assign_part<<<BB*GG*SPLIT, 256, 0, stream>>>(rec8, grec, Dp, ncand, clist, part_c, part_i, part_v);
  k_merge<<<2, 256, 0, stream>>>(grec, part_c, part_i, part_v, mcount, mgsum);
  k_losses<<<nBA/256, 256, 0, stream>>>(o8, o16, o32, rec8, grec, cand, mcount, mgsum, Dp, acc);
  k_fin<<<1, 64, 0, stream>>>(acc, out);
}